// Round 1
// baseline (4341.304 us; speedup 1.0000x reference)
//
#include <hip/hip_runtime.h>

#define T_STEPS 19
#define NBATCH  65536
#define RNN     256
#define EMB     128
#define KDIM    384   // RNN + EMB
#define ROWB    768   // KDIM * 2 bytes (LDS row stride)

typedef __bf16 bf16x8 __attribute__((ext_vector_type(8)));
typedef float  f32x16 __attribute__((ext_vector_type(16)));

__device__ __forceinline__ unsigned short f2bf(float f) {
    unsigned u = __float_as_uint(f);
    u += 0x7fffu + ((u >> 16) & 1u);
    return (unsigned short)(u >> 16);
}
__device__ __forceinline__ float sigm_(float x) {
    return 1.0f / (1.0f + __expf(-x));
}
__device__ __forceinline__ float tanh_(float x) {
    x = fminf(fmaxf(x, -12.0f), 12.0f);
    float e = __expf(-2.0f * x);
    return (1.0f - e) / (1.0f + e);
}

// ---- prep kernels: repack weights into MFMA-fragment order (bf16) in d_ws ----
// wcat fragment layout: group G = ((w*4+g)*24 + kk), lane l, 8 elems.
// j = g*256 + w*32 + (l&31); k = kk*16 + 8*(l>>5) + e;  value = k<256 ? Whh[j][k] : Wih[j][k-256]
__global__ void prep_wcat(const float* __restrict__ Whh, const float* __restrict__ Wih,
                          unsigned short* __restrict__ dst) {
    int tid = blockIdx.x * 256 + threadIdx.x;   // 49152 total
    int l  = tid & 63;
    int G  = tid >> 6;
    int kk = G % 24;
    int wg = G / 24;            // w*4+g
    int w  = wg >> 2, g = wg & 3;
    int j  = g * 256 + w * 32 + (l & 31);
    int kb = kk * 16 + 8 * (l >> 5);
    unsigned short v[8];
#pragma unroll
    for (int e = 0; e < 8; ++e) {
        int k = kb + e;
        float f = (k < 256) ? Whh[j * 256 + k] : Wih[j * 128 + (k - 256)];
        v[e] = f2bf(f);
    }
    uint4 pk;
    pk.x = (unsigned)v[0] | ((unsigned)v[1] << 16);
    pk.y = (unsigned)v[2] | ((unsigned)v[3] << 16);
    pk.z = (unsigned)v[4] | ((unsigned)v[5] << 16);
    pk.w = (unsigned)v[6] | ((unsigned)v[7] << 16);
    ((uint4*)dst)[tid] = pk;
}

// wout fragments: 16 kk-iters, 32-col tile (cols 5..31 zero-padded)
__global__ void prep_wout(const float* __restrict__ Wout, unsigned short* __restrict__ dst) {
    int tid = blockIdx.x * 256 + threadIdx.x;   // 1024 total
    if (tid >= 1024) return;
    int l  = tid & 63;
    int kk = tid >> 6;
    int q  = l & 31;
    int kb = kk * 16 + 8 * (l >> 5);
    unsigned short v[8];
#pragma unroll
    for (int e = 0; e < 8; ++e) {
        float f = (q < 5) ? Wout[q * 256 + kb + e] : 0.0f;
        v[e] = f2bf(f);
    }
    uint4 pk;
    pk.x = (unsigned)v[0] | ((unsigned)v[1] << 16);
    pk.y = (unsigned)v[2] | ((unsigned)v[3] << 16);
    pk.z = (unsigned)v[4] | ((unsigned)v[5] << 16);
    pk.w = (unsigned)v[6] | ((unsigned)v[7] << 16);
    ((uint4*)dst)[tid] = pk;
}

__global__ void prep_bias(const float* __restrict__ bih, const float* __restrict__ bhh,
                          float* __restrict__ dst) {
    int tid = blockIdx.x * 256 + threadIdx.x;
    if (tid < 1024) dst[tid] = bih[tid] + bhh[tid];
}

// ---- main persistent-over-T kernel: 1 block = 64 samples, 8 waves ----
__global__ __launch_bounds__(512, 2)
void lstm_main(const float* __restrict__ x_in, const float* __restrict__ h_in,
               const float* __restrict__ c_in, const int* __restrict__ mask,
               const float* __restrict__ W_emb, const float* __restrict__ b_emb,
               const float* __restrict__ b_out,
               const unsigned short* __restrict__ wcat_fr,
               const unsigned short* __restrict__ wout_fr,
               const float* __restrict__ bias_g,
               float* __restrict__ out) {
    __shared__ unsigned short A_lds[64 * KDIM];   // 48 KB: [row][k] bf16, XOR-swizzled

    const int tid   = threadIdx.x;
    const int lane  = tid & 63;
    const int w     = tid >> 6;        // wave 0..7
    const int base  = blockIdx.x * 64;
    const int col   = lane & 31;
    const int khalf = lane >> 5;       // 0/1
    const int ubase = w * 32 + col;    // hidden unit this lane owns in gate tiles

    float h_reg[2][16], c_reg[2][16];

    // init: load h0/c0 (fp32 regs) and write bf16 h into A_lds
#pragma unroll
    for (int mt = 0; mt < 2; ++mt)
#pragma unroll
        for (int r = 0; r < 16; ++r) {
            int row = mt * 32 + (r & 3) + 8 * (r >> 2) + 4 * khalf;
            float hv = h_in[(size_t)(base + row) * RNN + ubase];
            float cv = c_in[(size_t)(base + row) * RNN + ubase];
            h_reg[mt][r] = hv;
            c_reg[mt][r] = cv;
            int byte = row * ROWB + ubase * 2;
            byte ^= ((row & 7) << 4);
            A_lds[byte >> 1] = f2bf(hv);
        }

    float bias4[4];
#pragma unroll
    for (int g = 0; g < 4; ++g) bias4[g] = bias_g[g * 256 + ubase];
    const float bo = (col < 5) ? b_out[col] : 0.0f;

    const unsigned short* wf = wcat_fr + (size_t)w * (4 * 24 * 64 * 8);

    for (int t = 0; t < T_STEPS; ++t) {
        __syncthreads();  // bar0: prev Phase D reads done; prev B's e-reads done

        // ---- Phase A: e = relu(x @ W_emb + b_emb) -> A_lds k=256..383 ----
        {
            int row = tid >> 3;
            int jb  = (tid & 7) * 16;
            const float* xp = x_in + ((size_t)t * NBATCH + base + row) * 2;
            float x0 = xp[0], x1 = xp[1];
#pragma unroll
            for (int jj = 0; jj < 16; jj += 2) {
                int j = jb + jj;
                float e0 = fmaxf(fmaf(x0, W_emb[j],     fmaf(x1, W_emb[128 + j],     b_emb[j])),     0.0f);
                float e1 = fmaxf(fmaf(x0, W_emb[j + 1], fmaf(x1, W_emb[128 + j + 1], b_emb[j + 1])), 0.0f);
                int byte = row * ROWB + 512 + 2 * j;
                byte ^= ((row & 7) << 4);
                *(unsigned int*)((char*)A_lds + byte) =
                    (unsigned)f2bf(e0) | ((unsigned)f2bf(e1) << 16);
            }
        }
        __syncthreads();  // bar1: A_lds fully ready

        // ---- Phase B: gates = [h|e] @ Wcat^T + bias (MFMA) ----
        f32x16 acc[2][4];
#pragma unroll
        for (int mt = 0; mt < 2; ++mt)
#pragma unroll
            for (int g = 0; g < 4; ++g) {
                f32x16 z;
#pragma unroll
                for (int q = 0; q < 16; ++q) z[q] = bias4[g];
                acc[mt][g] = z;
            }
#pragma unroll 4
        for (int kk = 0; kk < 24; ++kk) {
            int row0 = col;
            int b0 = row0 * ROWB + kk * 32 + 16 * khalf; b0 ^= ((row0 & 7) << 4);
            bf16x8 a0 = *(const bf16x8*)((const char*)A_lds + b0);
            int row1 = 32 + col;
            int b1 = row1 * ROWB + kk * 32 + 16 * khalf; b1 ^= ((row1 & 7) << 4);
            bf16x8 a1 = *(const bf16x8*)((const char*)A_lds + b1);
#pragma unroll
            for (int g = 0; g < 4; ++g) {
                bf16x8 bfr = *(const bf16x8*)(wf + ((size_t)(g * 24 + kk) * 64 + lane) * 8);
                acc[0][g] = __builtin_amdgcn_mfma_f32_32x32x16_bf16(a0, bfr, acc[0][g], 0, 0, 0);
                acc[1][g] = __builtin_amdgcn_mfma_f32_32x32x16_bf16(a1, bfr, acc[1][g], 0, 0, 0);
            }
        }
        __syncthreads();  // bar2: all A_lds reads done before h overwrite

        // ---- Phase C: elementwise LSTM update (fp32), write carried h (bf16) ----
#pragma unroll
        for (int mt = 0; mt < 2; ++mt)
#pragma unroll
            for (int r = 0; r < 16; ++r) {
                int row = mt * 32 + (r & 3) + 8 * (r >> 2) + 4 * khalf;
                float iv = sigm_(acc[mt][0][r]);
                float fv = sigm_(acc[mt][1][r]);
                float gv = tanh_(acc[mt][2][r]);
                float ov = sigm_(acc[mt][3][r]);
                float cn = fmaf(fv, c_reg[mt][r], iv * gv);
                float hn = ov * tanh_(cn);
                int m = mask[(size_t)t * NBATCH + base + row];
                if (m) { c_reg[mt][r] = cn; h_reg[mt][r] = hn; }
                int byte = row * ROWB + ubase * 2;
                byte ^= ((row & 7) << 4);
                A_lds[byte >> 1] = f2bf(h_reg[mt][r]);
            }
        __syncthreads();  // bar3: new h visible

        // ---- Phase D: out = h @ Wout^T + b_out (waves 0,1; 32-col padded tile) ----
        if (w < 2) {
            f32x16 oacc;
#pragma unroll
            for (int q = 0; q < 16; ++q) oacc[q] = bo;
#pragma unroll
            for (int kk = 0; kk < 16; ++kk) {
                int row = w * 32 + col;
                int b0 = row * ROWB + kk * 32 + 16 * khalf; b0 ^= ((row & 7) << 4);
                bf16x8 a = *(const bf16x8*)((const char*)A_lds + b0);
                bf16x8 bfr = *(const bf16x8*)(wout_fr + ((size_t)kk * 64 + lane) * 8);
                oacc = __builtin_amdgcn_mfma_f32_32x32x16_bf16(a, bfr, oacc, 0, 0, 0);
            }
            if (col < 5) {
#pragma unroll
                for (int r = 0; r < 16; ++r) {
                    int row = w * 32 + (r & 3) + 8 * (r >> 2) + 4 * khalf;
                    int m = mask[(size_t)t * NBATCH + base + row];
                    out[((size_t)t * NBATCH + base + row) * 5 + col] = m ? oacc[r] : 0.0f;
                }
            }
        }
    }

    // ---- final states (fp32) ----
    float* hout = out + (size_t)T_STEPS * NBATCH * 5;
    float* cout = hout + (size_t)NBATCH * RNN;
#pragma unroll
    for (int mt = 0; mt < 2; ++mt)
#pragma unroll
        for (int r = 0; r < 16; ++r) {
            int row = mt * 32 + (r & 3) + 8 * (r >> 2) + 4 * khalf;
            hout[(size_t)(base + row) * RNN + ubase] = h_reg[mt][r];
            cout[(size_t)(base + row) * RNN + ubase] = c_reg[mt][r];
        }
}

extern "C" void kernel_launch(void* const* d_in, const int* in_sizes, int n_in,
                              void* d_out, int out_size, void* d_ws, size_t ws_size,
                              hipStream_t stream) {
    (void)in_sizes; (void)n_in; (void)out_size; (void)ws_size;
    const float* x_in = (const float*)d_in[0];
    const float* h0   = (const float*)d_in[1];
    const float* c0   = (const float*)d_in[2];
    const int*   mk   = (const int*)d_in[3];
    const float* Wemb = (const float*)d_in[4];
    const float* bemb = (const float*)d_in[5];
    const float* Wih  = (const float*)d_in[6];
    const float* bih  = (const float*)d_in[7];
    const float* Whh  = (const float*)d_in[8];
    const float* bhh  = (const float*)d_in[9];
    const float* Wout = (const float*)d_in[10];
    const float* bout = (const float*)d_in[11];

    unsigned short* wcat = (unsigned short*)d_ws;        // 786432 bf16 = 1.5MB/2 = 768KB... (elems*2B)
    unsigned short* wouf = wcat + 786432;                // 8192 bf16
    float*          bsg  = (float*)(wouf + 8192);        // 1024 f32

    prep_wcat<<<192, 256, 0, stream>>>(Whh, Wih, wcat);
    prep_wout<<<4, 256, 0, stream>>>(Wout, wouf);
    prep_bias<<<4, 256, 0, stream>>>(bih, bhh, bsg);

    float* outp = (float*)d_out;
    lstm_main<<<1024, 512, 0, stream>>>(x_in, h0, c0, mk, Wemb, bemb, bout,
                                        wcat, wouf, bsg, outp);
}

// Round 2
// 3806.638 us; speedup vs baseline: 1.1405x; 1.1405x over previous
//
#include <hip/hip_runtime.h>

#define T_STEPS 19
#define NBATCH  65536
#define RNN     256
#define EMB     128
#define KDIM    384   // RNN + EMB
#define ROWB    768   // KDIM * 2 bytes (LDS row stride)

typedef __bf16 bf16x8 __attribute__((ext_vector_type(8)));
typedef float  f32x16 __attribute__((ext_vector_type(16)));

__device__ __forceinline__ unsigned short f2bf(float f) {
    unsigned u = __float_as_uint(f);
    u += 0x7fffu + ((u >> 16) & 1u);
    return (unsigned short)(u >> 16);
}
__device__ __forceinline__ float sigm_(float x) {
    return 1.0f / (1.0f + __expf(-x));
}
__device__ __forceinline__ float tanh_(float x) {
    x = fminf(fmaxf(x, -12.0f), 12.0f);
    float e = __expf(-2.0f * x);
    return (1.0f - e) / (1.0f + e);
}

// ---- prep kernels: repack weights into MFMA-fragment order (bf16) in d_ws ----
__global__ void prep_wcat(const float* __restrict__ Whh, const float* __restrict__ Wih,
                          unsigned short* __restrict__ dst) {
    int tid = blockIdx.x * 256 + threadIdx.x;   // 49152 total
    int l  = tid & 63;
    int G  = tid >> 6;
    int kk = G % 24;
    int wg = G / 24;            // w*4+g
    int w  = wg >> 2, g = wg & 3;
    int j  = g * 256 + w * 32 + (l & 31);
    int kb = kk * 16 + 8 * (l >> 5);
    unsigned short v[8];
#pragma unroll
    for (int e = 0; e < 8; ++e) {
        int k = kb + e;
        float f = (k < 256) ? Whh[j * 256 + k] : Wih[j * 128 + (k - 256)];
        v[e] = f2bf(f);
    }
    uint4 pk;
    pk.x = (unsigned)v[0] | ((unsigned)v[1] << 16);
    pk.y = (unsigned)v[2] | ((unsigned)v[3] << 16);
    pk.z = (unsigned)v[4] | ((unsigned)v[5] << 16);
    pk.w = (unsigned)v[6] | ((unsigned)v[7] << 16);
    ((uint4*)dst)[tid] = pk;
}

__global__ void prep_wout(const float* __restrict__ Wout, unsigned short* __restrict__ dst) {
    int tid = blockIdx.x * 256 + threadIdx.x;   // 1024 total
    if (tid >= 1024) return;
    int l  = tid & 63;
    int kk = tid >> 6;
    int q  = l & 31;
    int kb = kk * 16 + 8 * (l >> 5);
    unsigned short v[8];
#pragma unroll
    for (int e = 0; e < 8; ++e) {
        float f = (q < 5) ? Wout[q * 256 + kb + e] : 0.0f;
        v[e] = f2bf(f);
    }
    uint4 pk;
    pk.x = (unsigned)v[0] | ((unsigned)v[1] << 16);
    pk.y = (unsigned)v[2] | ((unsigned)v[3] << 16);
    pk.z = (unsigned)v[4] | ((unsigned)v[5] << 16);
    pk.w = (unsigned)v[6] | ((unsigned)v[7] << 16);
    ((uint4*)dst)[tid] = pk;
}

__global__ void prep_bias(const float* __restrict__ bih, const float* __restrict__ bhh,
                          float* __restrict__ dst) {
    int tid = blockIdx.x * 256 + threadIdx.x;
    if (tid < 1024) dst[tid] = bih[tid] + bhh[tid];
}

// ---- main persistent-over-T kernel: 1 block = 64 samples, 8 waves ----
__global__ __launch_bounds__(512, 2)
void lstm_main(const float* __restrict__ x_in, const float* __restrict__ h_in,
               const float* __restrict__ c_in, const int* __restrict__ mask,
               const float* __restrict__ W_emb, const float* __restrict__ b_emb,
               const float* __restrict__ b_out,
               const unsigned short* __restrict__ wcat_fr,
               const unsigned short* __restrict__ wout_fr,
               const float* __restrict__ bias_g,
               float* __restrict__ out) {
    __shared__ unsigned short A_lds[64 * KDIM];   // 48 KB: [row][k] bf16, XOR-swizzled
    __shared__ float c_lds[64 * RNN];             // 64 KB: c state fp32, [row][unit]
    __shared__ int   m_lds[2][64];                // mask double-buffer

    const int tid   = threadIdx.x;
    const int lane  = tid & 63;
    const int w     = tid >> 6;        // wave 0..7
    const int base  = blockIdx.x * 64;
    const int col   = lane & 31;
    const int khalf = lane >> 5;       // 0/1
    const int ubase = w * 32 + col;    // hidden unit this lane owns in gate tiles

    float h_reg[2][16];                // fp32 h state (exact output path)

    // init: load h0/c0, write bf16 h + f32 c into LDS
#pragma unroll
    for (int mt = 0; mt < 2; ++mt)
#pragma unroll
        for (int r = 0; r < 16; ++r) {
            int row = mt * 32 + (r & 3) + 8 * (r >> 2) + 4 * khalf;
            float hv = h_in[(size_t)(base + row) * RNN + ubase];
            float cv = c_in[(size_t)(base + row) * RNN + ubase];
            h_reg[mt][r] = hv;
            c_lds[row * RNN + ubase] = cv;
            int byte = row * ROWB + ubase * 2;
            byte ^= ((row & 7) << 4);
            A_lds[byte >> 1] = f2bf(hv);
        }

    float bias4[4];
#pragma unroll
    for (int g = 0; g < 4; ++g) bias4[g] = bias_g[g * 256 + ubase];
    const float bo = (col < 5) ? b_out[col] : 0.0f;

    const unsigned short* wf = wcat_fr + (size_t)w * (4 * 24 * 64 * 8);

    for (int t = 0; t < T_STEPS; ++t) {
        // ---- Phase A: e = relu(x @ W_emb + b_emb) -> A_lds k=256..383; mask -> LDS ----
        {
            int row = tid >> 3;
            int jb  = (tid & 7) * 16;
            const float* xp = x_in + ((size_t)t * NBATCH + base + row) * 2;
            float x0 = xp[0], x1 = xp[1];
#pragma unroll
            for (int jj = 0; jj < 16; jj += 2) {
                int j = jb + jj;
                float e0 = fmaxf(fmaf(x0, W_emb[j],     fmaf(x1, W_emb[128 + j],     b_emb[j])),     0.0f);
                float e1 = fmaxf(fmaf(x0, W_emb[j + 1], fmaf(x1, W_emb[128 + j + 1], b_emb[j + 1])), 0.0f);
                int byte = row * ROWB + 512 + 2 * j;
                byte ^= ((row & 7) << 4);
                *(unsigned int*)((char*)A_lds + byte) =
                    (unsigned)f2bf(e0) | ((unsigned)f2bf(e1) << 16);
            }
            if (tid < 64) m_lds[t & 1][tid] = mask[(size_t)t * NBATCH + base + tid];
        }
        __syncthreads();  // bar1: A_lds + mask ready

        // ---- Phase B: gates = [h|e] @ Wcat^T + bias (MFMA) ----
        f32x16 acc[2][4];
#pragma unroll
        for (int mt = 0; mt < 2; ++mt)
#pragma unroll
            for (int g = 0; g < 4; ++g) {
                f32x16 z;
#pragma unroll
                for (int q = 0; q < 16; ++q) z[q] = bias4[g];
                acc[mt][g] = z;
            }
#pragma unroll 2
        for (int kk = 0; kk < 24; ++kk) {
            int row0 = col;
            int b0 = row0 * ROWB + kk * 32 + 16 * khalf; b0 ^= ((row0 & 7) << 4);
            bf16x8 a0 = *(const bf16x8*)((const char*)A_lds + b0);
            int row1 = 32 + col;
            int b1 = row1 * ROWB + kk * 32 + 16 * khalf; b1 ^= ((row1 & 7) << 4);
            bf16x8 a1 = *(const bf16x8*)((const char*)A_lds + b1);
#pragma unroll
            for (int g = 0; g < 4; ++g) {
                bf16x8 bfr = *(const bf16x8*)(wf + ((size_t)(g * 24 + kk) * 64 + lane) * 8);
                acc[0][g] = __builtin_amdgcn_mfma_f32_32x32x16_bf16(a0, bfr, acc[0][g], 0, 0, 0);
                acc[1][g] = __builtin_amdgcn_mfma_f32_32x32x16_bf16(a1, bfr, acc[1][g], 0, 0, 0);
            }
        }
        __syncthreads();  // bar2: all A_lds reads done before h/c overwrite

        // ---- Phase C: elementwise LSTM update (fp32); c in LDS, h in regs+LDS ----
#pragma unroll
        for (int mt = 0; mt < 2; ++mt)
#pragma unroll
            for (int r = 0; r < 16; ++r) {
                int row = mt * 32 + (r & 3) + 8 * (r >> 2) + 4 * khalf;
                float cv = c_lds[row * RNN + ubase];
                float iv = sigm_(acc[mt][0][r]);
                float fv = sigm_(acc[mt][1][r]);
                float gv = tanh_(acc[mt][2][r]);
                float ov = sigm_(acc[mt][3][r]);
                float cn = fmaf(fv, cv, iv * gv);
                float hn = ov * tanh_(cn);
                int m = m_lds[t & 1][row];
                if (m) {
                    c_lds[row * RNN + ubase] = cn;
                    h_reg[mt][r] = hn;
                }
                int byte = row * ROWB + ubase * 2;
                byte ^= ((row & 7) << 4);
                A_lds[byte >> 1] = f2bf(h_reg[mt][r]);
            }
        __syncthreads();  // bar3: new h visible

        // ---- Phase D: out = h @ Wout^T + b_out (waves 0,1; 32-col padded tile) ----
        if (w < 2) {
            f32x16 oacc;
#pragma unroll
            for (int q = 0; q < 16; ++q) oacc[q] = bo;
#pragma unroll
            for (int kk = 0; kk < 16; ++kk) {
                int row = w * 32 + col;
                int b0 = row * ROWB + kk * 32 + 16 * khalf; b0 ^= ((row & 7) << 4);
                bf16x8 a = *(const bf16x8*)((const char*)A_lds + b0);
                bf16x8 bfr = *(const bf16x8*)(wout_fr + ((size_t)kk * 64 + lane) * 8);
                oacc = __builtin_amdgcn_mfma_f32_32x32x16_bf16(a, bfr, oacc, 0, 0, 0);
            }
            if (col < 5) {
#pragma unroll
                for (int r = 0; r < 16; ++r) {
                    int row = w * 32 + (r & 3) + 8 * (r >> 2) + 4 * khalf;
                    int m = m_lds[t & 1][row];
                    out[((size_t)t * NBATCH + base + row) * 5 + col] = m ? oacc[r] : 0.0f;
                }
            }
        }
        // no barrier here: D reads h-region (k<256); next A writes e-region (k>=256)
        // and m_lds slot (t+1)&1 — disjoint. C(t+1)'s h-writes are behind bar1+bar2.
    }

    // ---- final states (fp32) ----
    float* hout = out + (size_t)T_STEPS * NBATCH * 5;
    float* cout = hout + (size_t)NBATCH * RNN;
#pragma unroll
    for (int mt = 0; mt < 2; ++mt)
#pragma unroll
        for (int r = 0; r < 16; ++r) {
            int row = mt * 32 + (r & 3) + 8 * (r >> 2) + 4 * khalf;
            hout[(size_t)(base + row) * RNN + ubase] = h_reg[mt][r];
            cout[(size_t)(base + row) * RNN + ubase] = c_lds[row * RNN + ubase];
        }
}

extern "C" void kernel_launch(void* const* d_in, const int* in_sizes, int n_in,
                              void* d_out, int out_size, void* d_ws, size_t ws_size,
                              hipStream_t stream) {
    (void)in_sizes; (void)n_in; (void)out_size; (void)ws_size;
    const float* x_in = (const float*)d_in[0];
    const float* h0   = (const float*)d_in[1];
    const float* c0   = (const float*)d_in[2];
    const int*   mk   = (const int*)d_in[3];
    const float* Wemb = (const float*)d_in[4];
    const float* bemb = (const float*)d_in[5];
    const float* Wih  = (const float*)d_in[6];
    const float* bih  = (const float*)d_in[7];
    const float* Whh  = (const float*)d_in[8];
    const float* bhh  = (const float*)d_in[9];
    const float* Wout = (const float*)d_in[10];
    const float* bout = (const float*)d_in[11];

    unsigned short* wcat = (unsigned short*)d_ws;        // 393216 bf16 = 768 KB
    unsigned short* wouf = wcat + 393216;                // 8192 bf16
    float*          bsg  = (float*)(wouf + 8192);        // 1024 f32

    prep_wcat<<<192, 256, 0, stream>>>(Whh, Wih, wcat);
    prep_wout<<<4, 256, 0, stream>>>(Wout, wouf);
    prep_bias<<<4, 256, 0, stream>>>(bih, bhh, bsg);

    float* outp = (float*)d_out;
    lstm_main<<<1024, 512, 0, stream>>>(x_in, h0, c0, mk, Wemb, bemb, bout,
                                        wcat, wouf, bsg, outp);
}